// Round 3
// baseline (647.134 us; speedup 1.0000x reference)
//
#include <hip/hip_runtime.h>

typedef unsigned short u16;
typedef __attribute__((ext_vector_type(8))) short bf16x8;
typedef __attribute__((ext_vector_type(4))) float f32x4;
typedef __attribute__((ext_vector_type(16))) float f32x16;

__device__ __forceinline__ u16 f2bf(float f) {
  union { float f; unsigned u; } x; x.f = f;
  return (u16)((x.u + 0x7FFFu + ((x.u >> 16) & 1u)) >> 16);
}
__device__ __forceinline__ float bf2f(u16 h) {
  union { unsigned u; float f; } x; x.u = ((unsigned)h) << 16; return x.f;
}

// Weight frag layout (bf16):
//  L0..L2 (32x32x16 frags): per (mt, ks): 64 lanes x 8 bf16 = 512 u16.
//    lane l -> row = mt*32 + (l&31), k = ks*16 + (l>>5)*8 + j
//  L3 (16x16x32 frags): lane l -> row = mt*16 + (l&15), k = ks*32 + (l>>4)*8 + j
// Offsets (u16 elems): L0 @0 (16mt x 40ks), L1 @327680 (8 x 32), L2 @458752 (4 x 16), L3 @491520 (4 x 4)

__global__ __launch_bounds__(256) void prep_kernel(
    const float* __restrict__ W0, const float* __restrict__ W1,
    const float* __restrict__ W2, const float* __restrict__ W3,
    const float* __restrict__ b0, const float* __restrict__ g0, const float* __restrict__ be0, const float* __restrict__ m0, const float* __restrict__ v0,
    const float* __restrict__ b1, const float* __restrict__ g1, const float* __restrict__ be1, const float* __restrict__ m1, const float* __restrict__ v1,
    const float* __restrict__ b2, const float* __restrict__ g2, const float* __restrict__ be2, const float* __restrict__ m2, const float* __restrict__ v2,
    const float* __restrict__ b3, const float* __restrict__ g3, const float* __restrict__ be3, const float* __restrict__ m3, const float* __restrict__ v3,
    u16* __restrict__ Wb, float* __restrict__ sc, float* __restrict__ sh)
{
  int i = blockIdx.x * 256 + threadIdx.x;
  if (i < 62464) {
    const float* Ws; int CIN, KS, local, dstb; bool f16 = false;
    if (i < 40960)      { local = i;         Ws = W0; CIN = 640; KS = 40; dstb = 0; }
    else if (i < 57344) { local = i - 40960; Ws = W1; CIN = 512; KS = 32; dstb = 327680; }
    else if (i < 61440) { local = i - 57344; Ws = W2; CIN = 256; KS = 16; dstb = 458752; }
    else                { local = i - 61440; Ws = W3; CIN = 128; KS = 4;  dstb = 491520; f16 = true; }
    int lane = local & 63, fi = local >> 6;
    int ks = fi % KS, mt = fi / KS;
    int row, k;
    if (!f16) { row = mt * 32 + (lane & 31); k = ks * 16 + (lane >> 5) * 8; }
    else      { row = mt * 16 + (lane & 15); k = ks * 32 + (lane >> 4) * 8; }
    const float* s = Ws + (size_t)row * CIN + k;
    bf16x8 pk;
    #pragma unroll
    for (int j = 0; j < 8; ++j) pk[j] = (short)f2bf(s[j]);
    *reinterpret_cast<bf16x8*>(Wb + dstb + (size_t)local * 8) = pk;
  }
  if (i < 960) {
    const float *B, *G, *BE, *M, *V; int c;
    if (i < 512)      { c = i;       B = b0; G = g0; BE = be0; M = m0; V = v0; }
    else if (i < 768) { c = i - 512; B = b1; G = g1; BE = be1; M = m1; V = v1; }
    else if (i < 896) { c = i - 768; B = b2; G = g2; BE = be2; M = m2; V = v2; }
    else              { c = i - 896; B = b3; G = g3; BE = be3; M = m3; V = v3; }
    float inv = G[c] / sqrtf(V[c] + 1e-5f);
    sc[i] = inv;
    sh[i] = (B[c] - M[c]) * inv + BE[c];
  }
}

// store helper for 32x32 acc tiles -> bf16 LDS tile [px][ch], stride rowB bytes,
// swizzle byte ^= (px&7)<<4.  C/D: col(px)=l&31, row(ch)= (r&3) + 8*(r>>2) + 4*(l>>5)
template<int MT, int NT>
__device__ __forceinline__ void store_act32(f32x16 (&acc)[MT][NT],
    const float* __restrict__ sc, const float* __restrict__ sh,
    int mrow0, int ntb, int lane, u16* __restrict__ dst, int rowB)
{
  const int l31 = lane & 31, khalf = lane >> 5;
  #pragma unroll
  for (int mi = 0; mi < MT; ++mi) {
    #pragma unroll
    for (int rq = 0; rq < 4; ++rq) {
      const int ch0 = mrow0 + mi * 32 + rq * 8 + khalf * 4;
      const f32x4 s4 = *reinterpret_cast<const f32x4*>(sc + ch0);
      const f32x4 h4 = *reinterpret_cast<const f32x4*>(sh + ch0);
      #pragma unroll
      for (int nt = 0; nt < NT; ++nt) {
        const int px = (ntb + nt) * 32 + l31;
        float r0 = fmaxf(acc[mi][nt][rq * 4 + 0] * s4[0] + h4[0], 0.f);
        float r1 = fmaxf(acc[mi][nt][rq * 4 + 1] * s4[1] + h4[1], 0.f);
        float r2 = fmaxf(acc[mi][nt][rq * 4 + 2] * s4[2] + h4[2], 0.f);
        float r3 = fmaxf(acc[mi][nt][rq * 4 + 3] * s4[3] + h4[3], 0.f);
        uint2 pk;
        pk.x = (unsigned)f2bf(r0) | ((unsigned)f2bf(r1) << 16);
        pk.y = (unsigned)f2bf(r2) | ((unsigned)f2bf(r3) << 16);
        const unsigned byte = ((unsigned)(px * rowB + ch0 * 2)) ^ ((unsigned)((px & 7) << 4));
        *reinterpret_cast<uint2*>(reinterpret_cast<char*>(dst) + byte) = pk;
      }
    }
  }
}

#define STAGE_DECL() \
  const float* gbase = gp + (size_t)b * (640u * 32768u) + (unsigned)(j0 + lane); \
  const unsigned swzL = (unsigned)((lane & 7) << 4); \
  const unsigned wbA = ((unsigned)(lane * 256 + w * 16)) ^ swzL; \
  const unsigned wbB = ((unsigned)(lane * 256 + (w + 8) * 16)) ^ swzL; \
  float v[16];

#define LOADC(c) { const float* s0_ = gbase + (size_t)((c) * 128 + w * 8) * 32768u; \
    const float* s1_ = s0_ + (size_t)(64u * 32768u); \
    _Pragma("unroll") for (int kk = 0; kk < 8; ++kk) v[kk]     = s0_[(size_t)kk * 32768u]; \
    _Pragma("unroll") for (int kk = 0; kk < 8; ++kk) v[8 + kk] = s1_[(size_t)kk * 32768u]; }

#define WRITEC() { bf16x8 pa, pb; \
    _Pragma("unroll") for (int kk = 0; kk < 8; ++kk) { pa[kk] = (short)f2bf(v[kk]); pb[kk] = (short)f2bf(v[8 + kk]); } \
    *reinterpret_cast<bf16x8*>(reinterpret_cast<char*>(Xs) + wbA) = pa; \
    *reinterpret_cast<bf16x8*>(reinterpret_cast<char*>(Xs) + wbB) = pb; }

// phase0 body (shared by main + diag): 640->512, 5 chunks of 128 ch, A-ring depth 2
#define PHASE0_BODY() \
  f32x16 acc0[2][2] = {}; \
  LOADC(0); WRITEC(); \
  __syncthreads(); \
  const u16* A0 = Wb + (size_t)(2 * w) * 40 * 512 + lane * 8; \
  const u16* A1 = Wb + (size_t)(2 * w + 1) * 40 * 512 + lane * 8; \
  _Pragma("unroll 1") \
  for (int c = 0; c < 5; ++c) { \
    bf16x8 ar[2][2]; \
    ar[0][0] = *reinterpret_cast<const bf16x8*>(A0 + (c * 8 + 0) * 512); \
    ar[0][1] = *reinterpret_cast<const bf16x8*>(A1 + (c * 8 + 0) * 512); \
    ar[1][0] = *reinterpret_cast<const bf16x8*>(A0 + (c * 8 + 1) * 512); \
    ar[1][1] = *reinterpret_cast<const bf16x8*>(A1 + (c * 8 + 1) * 512); \
    if (c < 4) LOADC(c + 1); \
    _Pragma("unroll") \
    for (int ksl = 0; ksl < 8; ++ksl) { \
      const unsigned kb = (unsigned)(ksl * 32 + khalf * 16); \
      const unsigned sw = (unsigned)((l31 & 7) << 4); \
      bf16x8 bb0 = *reinterpret_cast<const bf16x8*>(reinterpret_cast<const char*>(Xs) + (((unsigned)(l31 * 256) + kb) ^ sw)); \
      bf16x8 bb1 = *reinterpret_cast<const bf16x8*>(reinterpret_cast<const char*>(Xs) + (((unsigned)((l31 + 32) * 256) + kb) ^ sw)); \
      acc0[0][0] = __builtin_amdgcn_mfma_f32_32x32x16_bf16(ar[ksl & 1][0], bb0, acc0[0][0], 0, 0, 0); \
      acc0[0][1] = __builtin_amdgcn_mfma_f32_32x32x16_bf16(ar[ksl & 1][0], bb1, acc0[0][1], 0, 0, 0); \
      acc0[1][0] = __builtin_amdgcn_mfma_f32_32x32x16_bf16(ar[ksl & 1][1], bb0, acc0[1][0], 0, 0, 0); \
      acc0[1][1] = __builtin_amdgcn_mfma_f32_32x32x16_bf16(ar[ksl & 1][1], bb1, acc0[1][1], 0, 0, 0); \
      if (ksl < 6) { \
        ar[ksl & 1][0] = *reinterpret_cast<const bf16x8*>(A0 + (c * 8 + ksl + 2) * 512); \
        ar[ksl & 1][1] = *reinterpret_cast<const bf16x8*>(A1 + (c * 8 + ksl + 2) * 512); \
      } \
    } \
    if (c < 4) { __syncthreads(); WRITEC(); __syncthreads(); } \
  } \
  store_act32<2, 2>(acc0, sc, sh, w * 64, 0, lane, Y0s, 1024); \
  __syncthreads();

__global__ __launch_bounds__(512, 4) void fused4_kernel(
    const float* __restrict__ gp, const u16* __restrict__ Wb,
    const float* __restrict__ sc, const float* __restrict__ sh,
    u16* __restrict__ x3)
{
  __shared__ u16 smem[40960];   // 80 KB
  u16* Xs  = smem;              // [64px][128ch] stride 256B (swz); later Y2
  u16* Y0s = smem + 8192;       // [64px][512ch] stride 1024B (swz); later Y1 (512B)

  const int tid  = threadIdx.x;
  const int lane = tid & 63;
  const int w    = tid >> 6;
  const int l31  = lane & 31, khalf = lane >> 5;

  const int b  = blockIdx.x >> 9;
  const int jt = blockIdx.x & 511;
  const int j0 = jt << 6;

  STAGE_DECL();
  PHASE0_BODY();

  // ---- phase 1: 512 -> 256  (wave w: rows w*32..+31, both 32-px tiles), ring depth 4
  {
    f32x16 acc1[1][2] = {};
    const u16* A = Wb + 327680 + (size_t)w * 32 * 512 + lane * 8;
    bf16x8 ar4[4];
    #pragma unroll
    for (int q = 0; q < 4; ++q) ar4[q] = *reinterpret_cast<const bf16x8*>(A + q * 512);
    #pragma unroll
    for (int ks = 0; ks < 32; ++ks) {
      const unsigned kb = (unsigned)(ks * 32 + khalf * 16);
      const unsigned sw = (unsigned)((l31 & 7) << 4);
      bf16x8 bb0 = *reinterpret_cast<const bf16x8*>(reinterpret_cast<const char*>(Y0s) + (((unsigned)(l31 * 1024) + kb) ^ sw));
      bf16x8 bb1 = *reinterpret_cast<const bf16x8*>(reinterpret_cast<const char*>(Y0s) + (((unsigned)((l31 + 32) * 1024) + kb) ^ sw));
      acc1[0][0] = __builtin_amdgcn_mfma_f32_32x32x16_bf16(ar4[ks & 3], bb0, acc1[0][0], 0, 0, 0);
      acc1[0][1] = __builtin_amdgcn_mfma_f32_32x32x16_bf16(ar4[ks & 3], bb1, acc1[0][1], 0, 0, 0);
      if (ks < 28) ar4[ks & 3] = *reinterpret_cast<const bf16x8*>(A + (ks + 4) * 512);
    }
    __syncthreads();   // all waves done reading Y0
    store_act32<1, 2>(acc1, sc + 512, sh + 512, w * 32, 0, lane, Y0s, 512);   // Y1 overlays Y0
    __syncthreads();
  }

  // ---- phase 2: 256 -> 128  (wave w: mt=w&3 rows, nt=w>>2 32-px tile), ring depth 4
  {
    f32x16 acc2[1][1] = {};
    const u16* A = Wb + 458752 + (size_t)(w & 3) * 16 * 512 + lane * 8;
    const int pxb = (w >> 2) * 32;
    bf16x8 ar4[4];
    #pragma unroll
    for (int q = 0; q < 4; ++q) ar4[q] = *reinterpret_cast<const bf16x8*>(A + q * 512);
    #pragma unroll
    for (int ks = 0; ks < 16; ++ks) {
      const unsigned kb = (unsigned)(ks * 32 + khalf * 16);
      const unsigned sw = (unsigned)((l31 & 7) << 4);
      bf16x8 bb0 = *reinterpret_cast<const bf16x8*>(reinterpret_cast<const char*>(Y0s) + (((unsigned)((pxb + l31) * 512) + kb) ^ sw));
      acc2[0][0] = __builtin_amdgcn_mfma_f32_32x32x16_bf16(ar4[ks & 3], bb0, acc2[0][0], 0, 0, 0);
      if (ks < 12) ar4[ks & 3] = *reinterpret_cast<const bf16x8*>(A + (ks + 4) * 512);
    }
    store_act32<1, 1>(acc2, sc + 768, sh + 768, (w & 3) * 32, w >> 2, lane, Xs, 256);  // Y2 -> Xs region
    __syncthreads();
  }

  // ---- phase 3: 128 -> 64  (16x16x32; wave w: mt=w&3, n-tiles 2*(w>>2)+{0,1})
  {
    const int r16 = lane & 15, g = lane >> 4;
    f32x4 acc3[2] = {};
    const u16* A = Wb + 491520 + (size_t)(w & 3) * 4 * 512 + lane * 8;
    bf16x8 a4[4];
    #pragma unroll
    for (int q = 0; q < 4; ++q) a4[q] = *reinterpret_cast<const bf16x8*>(A + q * 512);
    const int ntb = (w >> 2) * 2;
    #pragma unroll
    for (int ks = 0; ks < 4; ++ks) {
      #pragma unroll
      for (int nt = 0; nt < 2; ++nt) {
        const int px = (ntb + nt) * 16 + r16;
        const unsigned byte = ((unsigned)(px * 256 + ks * 64 + g * 16)) ^ ((unsigned)((px & 7) << 4));
        bf16x8 bb = *reinterpret_cast<const bf16x8*>(reinterpret_cast<const char*>(Xs) + byte);
        acc3[nt] = __builtin_amdgcn_mfma_f32_16x16x32_bf16(a4[ks], bb, acc3[nt], 0, 0, 0);
      }
    }
    const int c0 = (w & 3) * 16 + g * 4;
    const f32x4 s4 = *reinterpret_cast<const f32x4*>(sc + 896 + c0);
    const f32x4 h4 = *reinterpret_cast<const f32x4*>(sh + 896 + c0);
    u16* x3b = x3 + ((size_t)b << 21) + j0;
    #pragma unroll
    for (int nt = 0; nt < 2; ++nt) {
      const int n = (ntb + nt) * 16 + r16;
      #pragma unroll
      for (int r = 0; r < 4; ++r) {
        float vv = fmaxf(acc3[nt][r] * s4[r] + h4[r], 0.f);
        x3b[(size_t)(c0 + r) * 32768 + n] = f2bf(vv);
      }
    }
  }
}

// DIAGNOSTIC: phase0 only (same code), result copied out to defeat DCE.
// Writes into the x3 buffer, which the real fused4_kernel fully overwrites afterwards.
__global__ __launch_bounds__(512, 4) void fused4_p0diag(
    const float* __restrict__ gp, const u16* __restrict__ Wb,
    const float* __restrict__ sc, const float* __restrict__ sh,
    u16* __restrict__ x3)
{
  __shared__ u16 smem[40960];
  u16* Xs  = smem;
  u16* Y0s = smem + 8192;

  const int tid  = threadIdx.x;
  const int lane = tid & 63;
  const int w    = tid >> 6;
  const int l31  = lane & 31, khalf = lane >> 5;

  const int b  = blockIdx.x >> 9;
  const int jt = blockIdx.x & 511;
  const int j0 = jt << 6;

  STAGE_DECL();
  PHASE0_BODY();

  // copy 8B/thread of Y0 out (keep-alive; 4096*512*8B = 16.8MB < x3 size)
  uint2* dst = reinterpret_cast<uint2*>(x3) + ((size_t)blockIdx.x * 512 + tid);
  *dst = *reinterpret_cast<const uint2*>(reinterpret_cast<const char*>(Y0s) + tid * 8);
}

// ---------------- softmax over K + weighted sum with xyz ----------------
__global__ __launch_bounds__(256) void softmax_ws_kernel(
    const u16* __restrict__ x3, const float* __restrict__ xyz,
    float* __restrict__ out)
{
  const int tid = blockIdx.x * 256 + threadIdx.x;   // 0 .. 524287
  const int b = tid >> 16;
  const int rem = tid & 65535;
  const int d = rem >> 10;
  const int s = rem & 1023;

  const u16* xp = x3 + ((size_t)(b * 64 + d) << 15) + s;
  float p[32];
  float mx = -1e30f;
  #pragma unroll
  for (int k = 0; k < 32; ++k) { p[k] = bf2f(xp[(size_t)k << 10]); mx = fmaxf(mx, p[k]); }
  float sum = 0.f;
  #pragma unroll
  for (int k = 0; k < 32; ++k) { p[k] = __expf(p[k] - mx); sum += p[k]; }
  const float inv = 1.0f / sum;

  const float* zp = xyz + (size_t)b * (3 * 32768) + s;
  #pragma unroll
  for (int c = 0; c < 3; ++c) {
    float a = 0.f;
    #pragma unroll
    for (int k = 0; k < 32; ++k) a += p[k] * zp[c * 32768 + (k << 10)];
    out[((size_t)((b * 3 + c) * 64 + d) << 10) + s] = a * inv;
  }
}

// ---------------- launcher ----------------
extern "C" void kernel_launch(void* const* d_in, const int* in_sizes, int n_in,
                              void* d_out, int out_size, void* d_ws, size_t ws_size,
                              hipStream_t stream) {
  const float* xyz = (const float*)d_in[0];
  const float* gp  = (const float*)d_in[1];
  const float* W0 = (const float*)d_in[2];
  const float* W1 = (const float*)d_in[8];
  const float* W2 = (const float*)d_in[14];
  const float* W3 = (const float*)d_in[20];

  char* ws = (char*)d_ws;
  u16*   Wb = (u16*)ws;                       // 499712 bf16 -> 999424 B
  float* sc = (float*)(ws + 999424);          // 960 f32
  float* sh = (float*)(ws + 1003264);         // 960 f32
  u16*   x3 = (u16*)(ws + 1007104);           // 8*64*32768 bf16 = 33.5 MB

  prep_kernel<<<245, 256, 0, stream>>>(
      W0, W1, W2, W3,
      (const float*)d_in[3],  (const float*)d_in[4],  (const float*)d_in[5],  (const float*)d_in[6],  (const float*)d_in[7],
      (const float*)d_in[9],  (const float*)d_in[10], (const float*)d_in[11], (const float*)d_in[12], (const float*)d_in[13],
      (const float*)d_in[15], (const float*)d_in[16], (const float*)d_in[17], (const float*)d_in[18], (const float*)d_in[19],
      (const float*)d_in[21], (const float*)d_in[22], (const float*)d_in[23], (const float*)d_in[24], (const float*)d_in[25],
      Wb, sc, sh);

  // diagnostic dispatch (phase0 only) -- junk into x3, overwritten below
  fused4_p0diag<<<4096, 512, 0, stream>>>(gp, Wb, sc, sh, x3);

  fused4_kernel<<<4096, 512, 0, stream>>>(gp, Wb, sc, sh, x3);

  softmax_ws_kernel<<<2048, 256, 0, stream>>>(x3, xyz, (float*)d_out);
}

// Round 4
// 360.263 us; speedup vs baseline: 1.7963x; 1.7963x over previous
//
#include <hip/hip_runtime.h>

typedef unsigned short u16;
typedef __attribute__((ext_vector_type(8))) short bf16x8;
typedef __attribute__((ext_vector_type(4))) float f32x4;
typedef __attribute__((ext_vector_type(16))) float f32x16;

__device__ __forceinline__ u16 f2bf(float f) {
  union { float f; unsigned u; } x; x.f = f;
  return (u16)((x.u + 0x7FFFu + ((x.u >> 16) & 1u)) >> 16);
}
__device__ __forceinline__ float bf2f(u16 h) {
  union { unsigned u; float f; } x; x.u = ((unsigned)h) << 16; return x.f;
}

// Weight frag layout (bf16):
//  L0..L2 (32x32x16 frags): per (mt, ks): 64 lanes x 8 bf16 = 512 u16.
//    lane l -> row = mt*32 + (l&31), k = ks*16 + (l>>5)*8 + j
//  L3 (16x16x32 frags): lane l -> row = mt*16 + (l&15), k = ks*32 + (l>>4)*8 + j
// Offsets (u16 elems): L0 @0 (16mt x 40ks), L1 @327680 (8 x 32), L2 @458752 (4 x 16), L3 @491520 (4 x 4)

__global__ __launch_bounds__(256) void prep_kernel(
    const float* __restrict__ W0, const float* __restrict__ W1,
    const float* __restrict__ W2, const float* __restrict__ W3,
    const float* __restrict__ b0, const float* __restrict__ g0, const float* __restrict__ be0, const float* __restrict__ m0, const float* __restrict__ v0,
    const float* __restrict__ b1, const float* __restrict__ g1, const float* __restrict__ be1, const float* __restrict__ m1, const float* __restrict__ v1,
    const float* __restrict__ b2, const float* __restrict__ g2, const float* __restrict__ be2, const float* __restrict__ m2, const float* __restrict__ v2,
    const float* __restrict__ b3, const float* __restrict__ g3, const float* __restrict__ be3, const float* __restrict__ m3, const float* __restrict__ v3,
    u16* __restrict__ Wb, float* __restrict__ sc, float* __restrict__ sh)
{
  int i = blockIdx.x * 256 + threadIdx.x;
  if (i < 62464) {
    const float* Ws; int CIN, KS, local, dstb; bool f16 = false;
    if (i < 40960)      { local = i;         Ws = W0; CIN = 640; KS = 40; dstb = 0; }
    else if (i < 57344) { local = i - 40960; Ws = W1; CIN = 512; KS = 32; dstb = 327680; }
    else if (i < 61440) { local = i - 57344; Ws = W2; CIN = 256; KS = 16; dstb = 458752; }
    else                { local = i - 61440; Ws = W3; CIN = 128; KS = 4;  dstb = 491520; f16 = true; }
    int lane = local & 63, fi = local >> 6;
    int ks = fi % KS, mt = fi / KS;
    int row, k;
    if (!f16) { row = mt * 32 + (lane & 31); k = ks * 16 + (lane >> 5) * 8; }
    else      { row = mt * 16 + (lane & 15); k = ks * 32 + (lane >> 4) * 8; }
    const float* s = Ws + (size_t)row * CIN + k;
    bf16x8 pk;
    #pragma unroll
    for (int j = 0; j < 8; ++j) pk[j] = (short)f2bf(s[j]);
    *reinterpret_cast<bf16x8*>(Wb + dstb + (size_t)local * 8) = pk;
  }
  if (i < 960) {
    const float *B, *G, *BE, *M, *V; int c;
    if (i < 512)      { c = i;       B = b0; G = g0; BE = be0; M = m0; V = v0; }
    else if (i < 768) { c = i - 512; B = b1; G = g1; BE = be1; M = m1; V = v1; }
    else if (i < 896) { c = i - 768; B = b2; G = g2; BE = be2; M = m2; V = v2; }
    else              { c = i - 896; B = b3; G = g3; BE = be3; M = m3; V = v3; }
    float inv = G[c] / sqrtf(V[c] + 1e-5f);
    sc[i] = inv;
    sh[i] = (B[c] - M[c]) * inv + BE[c];
  }
}

// store helper for 32x32 acc tiles -> bf16 LDS tile [px][ch], stride rowB bytes,
// swizzle byte ^= (px&7)<<4.  C/D: col(px)=l&31, row(ch)= (r&3) + 8*(r>>2) + 4*(l>>5)
template<int MT, int NT>
__device__ __forceinline__ void store_act32(f32x16 (&acc)[MT][NT],
    const float* __restrict__ sc, const float* __restrict__ sh,
    int mrow0, int ntb, int lane, u16* __restrict__ dst, int rowB)
{
  const int l31 = lane & 31, khalf = lane >> 5;
  #pragma unroll
  for (int mi = 0; mi < MT; ++mi) {
    #pragma unroll
    for (int rq = 0; rq < 4; ++rq) {
      const int ch0 = mrow0 + mi * 32 + rq * 8 + khalf * 4;
      const f32x4 s4 = *reinterpret_cast<const f32x4*>(sc + ch0);
      const f32x4 h4 = *reinterpret_cast<const f32x4*>(sh + ch0);
      #pragma unroll
      for (int nt = 0; nt < NT; ++nt) {
        const int px = (ntb + nt) * 32 + l31;
        float r0 = fmaxf(acc[mi][nt][rq * 4 + 0] * s4[0] + h4[0], 0.f);
        float r1 = fmaxf(acc[mi][nt][rq * 4 + 1] * s4[1] + h4[1], 0.f);
        float r2 = fmaxf(acc[mi][nt][rq * 4 + 2] * s4[2] + h4[2], 0.f);
        float r3 = fmaxf(acc[mi][nt][rq * 4 + 3] * s4[3] + h4[3], 0.f);
        uint2 pk;
        pk.x = (unsigned)f2bf(r0) | ((unsigned)f2bf(r1) << 16);
        pk.y = (unsigned)f2bf(r2) | ((unsigned)f2bf(r3) << 16);
        const unsigned byte = ((unsigned)(px * rowB + ch0 * 2)) ^ ((unsigned)((px & 7) << 4));
        *reinterpret_cast<uint2*>(reinterpret_cast<char*>(dst) + byte) = pk;
      }
    }
  }
}

__device__ __forceinline__ void load64(const float* __restrict__ gbase, int c, int w, float (&v)[8]) {
  const float* s = gbase + (size_t)(c * 64 + w * 8) * 32768u;
  #pragma unroll
  for (int kk = 0; kk < 8; ++kk) v[kk] = s[(size_t)kk * 32768u];
}
__device__ __forceinline__ void write64(float (&v)[8], char* __restrict__ buf, unsigned wb) {
  bf16x8 pk;
  #pragma unroll
  for (int kk = 0; kk < 8; ++kk) pk[kk] = (short)f2bf(v[kk]);
  *reinterpret_cast<bf16x8*>(buf + wb) = pk;
}

// one 64-ch chunk of phase0 MFMA: 4 k-steps, acc[2][2], A-ring depth 2
#define P0_MFMA(XB, c) { \
  bf16x8 ar[2][2]; \
  ar[0][0] = *reinterpret_cast<const bf16x8*>(A0 + ((c) * 4 + 0) * 512); \
  ar[0][1] = *reinterpret_cast<const bf16x8*>(A1 + ((c) * 4 + 0) * 512); \
  ar[1][0] = *reinterpret_cast<const bf16x8*>(A0 + ((c) * 4 + 1) * 512); \
  ar[1][1] = *reinterpret_cast<const bf16x8*>(A1 + ((c) * 4 + 1) * 512); \
  __builtin_amdgcn_s_setprio(1); \
  _Pragma("unroll") \
  for (int ksl = 0; ksl < 4; ++ksl) { \
    const unsigned base = ((unsigned)(l31 * 128 + ksl * 32 + khalf * 16)) ^ sw; \
    bf16x8 bb0 = *reinterpret_cast<const bf16x8*>((XB) + base); \
    bf16x8 bb1 = *reinterpret_cast<const bf16x8*>((XB) + base + 4096); \
    acc0[0][0] = __builtin_amdgcn_mfma_f32_32x32x16_bf16(ar[ksl & 1][0], bb0, acc0[0][0], 0, 0, 0); \
    acc0[0][1] = __builtin_amdgcn_mfma_f32_32x32x16_bf16(ar[ksl & 1][0], bb1, acc0[0][1], 0, 0, 0); \
    acc0[1][0] = __builtin_amdgcn_mfma_f32_32x32x16_bf16(ar[ksl & 1][1], bb0, acc0[1][0], 0, 0, 0); \
    acc0[1][1] = __builtin_amdgcn_mfma_f32_32x32x16_bf16(ar[ksl & 1][1], bb1, acc0[1][1], 0, 0, 0); \
    if (ksl < 2) { \
      ar[ksl & 1][0] = *reinterpret_cast<const bf16x8*>(A0 + ((c) * 4 + ksl + 2) * 512); \
      ar[ksl & 1][1] = *reinterpret_cast<const bf16x8*>(A1 + ((c) * 4 + ksl + 2) * 512); \
    } \
  } \
  __builtin_amdgcn_s_setprio(0); \
}

// LDS map (80 KB, 2 blocks/CU):
//   bytes [0,8192)      XsA  [64px][64ch] bf16, stride 128B (swz)   } phase0 dbuf;
//   bytes [8192,16384)  XsB  (same)                                 } later Y2 [64][128] stride 256B
//   bytes [16384,81920) Y0s  [64px][512ch] bf16, stride 1024B (swz); later Y1 (stride 512B)
__global__ __launch_bounds__(512, 4) void fused4_kernel(
    const float* __restrict__ gp, const u16* __restrict__ Wb,
    const float* __restrict__ sc, const float* __restrict__ sh,
    u16* __restrict__ x3)
{
  __shared__ u16 smem[40960];   // 80 KB
  char* XsA = reinterpret_cast<char*>(smem);
  char* XsB = XsA + 8192;
  u16*  Y0s = smem + 8192;      // byte 16384

  const int tid  = threadIdx.x;
  const int lane = tid & 63;
  const int w    = tid >> 6;
  const int l31  = lane & 31, khalf = lane >> 5;
  const unsigned sw = (unsigned)((l31 & 7) << 4);

  const int b  = blockIdx.x >> 9;
  const int jt = blockIdx.x & 511;
  const int j0 = jt << 6;

  // staging: thread owns px = lane, channels w*8..w*8+7 of each 64-ch chunk
  const float* gbase = gp + (size_t)b * (640u * 32768u) + (unsigned)(j0 + lane);
  const unsigned wbyte = ((unsigned)(lane * 128 + w * 16)) ^ ((unsigned)((lane & 7) << 4));

  const u16* A0 = Wb + (size_t)(2 * w) * (40 * 512) + lane * 8;
  const u16* A1 = A0 + (size_t)(40 * 512);

  float vA[8], vB[8];
  f32x16 acc0[2][2] = {};

  // ---- phase 0 prologue
  load64(gbase, 0, w, vA);
  write64(vA, XsA, wbyte);          // chunk 0 -> bufA
  load64(gbase, 1, w, vB);
  __syncthreads();

  // ---- phase 0 main: 10 chunks, dbuf, 1 barrier/chunk (even/odd explicit)
  #pragma unroll 1
  for (int c2 = 0; c2 < 5; ++c2) {
    const int ce = 2 * c2;
    {
      if (ce < 8) load64(gbase, ce + 2, w, vA);
      write64(vB, XsB, wbyte);                    // chunk ce+1 -> bufB
      P0_MFMA(XsA, ce);
      __syncthreads();
    }
    const int co = 2 * c2 + 1;
    {
      if (co < 8) load64(gbase, co + 2, w, vB);
      if (co < 9) write64(vA, XsA, wbyte);        // chunk co+1 -> bufA
      P0_MFMA(XsB, co);
      if (co < 9) __syncthreads();
    }
  }
  // Y0 store (Y0s region untouched above; per-wave disjoint rows)
  store_act32<2, 2>(acc0, sc, sh, w * 64, 0, lane, Y0s, 1024);
  __syncthreads();

  // ---- phase 1: 512 -> 256  (wave w: rows w*32..+31, both 32-px tiles), ring depth 8
  {
    f32x16 acc1[1][2] = {};
    const u16* A = Wb + 327680 + (size_t)w * (32 * 512) + lane * 8;
    bf16x8 ar8[8];
    #pragma unroll
    for (int q = 0; q < 8; ++q) ar8[q] = *reinterpret_cast<const bf16x8*>(A + q * 512);
    __builtin_amdgcn_s_setprio(1);
    #pragma unroll
    for (int ks = 0; ks < 32; ++ks) {
      const unsigned kb = (unsigned)(ks * 32 + khalf * 16);
      bf16x8 bb0 = *reinterpret_cast<const bf16x8*>(reinterpret_cast<const char*>(Y0s) + (((unsigned)(l31 * 1024) + kb) ^ sw));
      bf16x8 bb1 = *reinterpret_cast<const bf16x8*>(reinterpret_cast<const char*>(Y0s) + (((unsigned)((l31 + 32) * 1024) + kb) ^ sw));
      acc1[0][0] = __builtin_amdgcn_mfma_f32_32x32x16_bf16(ar8[ks & 7], bb0, acc1[0][0], 0, 0, 0);
      acc1[0][1] = __builtin_amdgcn_mfma_f32_32x32x16_bf16(ar8[ks & 7], bb1, acc1[0][1], 0, 0, 0);
      if (ks < 24) ar8[ks & 7] = *reinterpret_cast<const bf16x8*>(A + (ks + 8) * 512);
    }
    __builtin_amdgcn_s_setprio(0);
    __syncthreads();   // all waves done reading Y0
    store_act32<1, 2>(acc1, sc + 512, sh + 512, w * 32, 0, lane, Y0s, 512);   // Y1 overlays Y0
    __syncthreads();
  }

  // ---- phase 2: 256 -> 128  (wave w: mt=w&3 rows, nt=w>>2 32-px tile), ring depth 8
  {
    f32x16 acc2[1][1] = {};
    const u16* A = Wb + 458752 + (size_t)(w & 3) * (16 * 512) + lane * 8;
    const int pxb = (w >> 2) * 32;
    bf16x8 ar8[8];
    #pragma unroll
    for (int q = 0; q < 8; ++q) ar8[q] = *reinterpret_cast<const bf16x8*>(A + q * 512);
    __builtin_amdgcn_s_setprio(1);
    #pragma unroll
    for (int ks = 0; ks < 16; ++ks) {
      const unsigned kb = (unsigned)(ks * 32 + khalf * 16);
      bf16x8 bb0 = *reinterpret_cast<const bf16x8*>(reinterpret_cast<const char*>(Y0s) + (((unsigned)((pxb + l31) * 512) + kb) ^ sw));
      acc2[0][0] = __builtin_amdgcn_mfma_f32_32x32x16_bf16(ar8[ks & 7], bb0, acc2[0][0], 0, 0, 0);
      if (ks < 8) ar8[ks & 7] = *reinterpret_cast<const bf16x8*>(A + (ks + 8) * 512);
    }
    __builtin_amdgcn_s_setprio(0);
    // Y2 -> Xs region (bytes 0..16383; not read since phase 0)
    store_act32<1, 1>(acc2, sc + 768, sh + 768, (w & 3) * 32, w >> 2, lane, smem, 256);
    __syncthreads();
  }

  // ---- phase 3: 128 -> 64  (16x16x32; wave w: mt=w&3, n-tiles 2*(w>>2)+{0,1})
  {
    const int r16 = lane & 15, g = lane >> 4;
    f32x4 acc3[2] = {};
    const u16* A = Wb + 491520 + (size_t)(w & 3) * (4 * 512) + lane * 8;
    bf16x8 a4[4];
    #pragma unroll
    for (int q = 0; q < 4; ++q) a4[q] = *reinterpret_cast<const bf16x8*>(A + q * 512);
    const int ntb = (w >> 2) * 2;
    __builtin_amdgcn_s_setprio(1);
    #pragma unroll
    for (int ks = 0; ks < 4; ++ks) {
      #pragma unroll
      for (int nt = 0; nt < 2; ++nt) {
        const int px = (ntb + nt) * 16 + r16;
        const unsigned byte = ((unsigned)(px * 256 + ks * 64 + g * 16)) ^ ((unsigned)((px & 7) << 4));
        bf16x8 bb = *reinterpret_cast<const bf16x8*>(reinterpret_cast<const char*>(smem) + byte);
        acc3[nt] = __builtin_amdgcn_mfma_f32_16x16x32_bf16(a4[ks], bb, acc3[nt], 0, 0, 0);
      }
    }
    __builtin_amdgcn_s_setprio(0);
    const int c0 = (w & 3) * 16 + g * 4;
    const f32x4 s4 = *reinterpret_cast<const f32x4*>(sc + 896 + c0);
    const f32x4 h4 = *reinterpret_cast<const f32x4*>(sh + 896 + c0);
    u16* x3b = x3 + ((size_t)b << 21) + j0;
    #pragma unroll
    for (int nt = 0; nt < 2; ++nt) {
      const int n = (ntb + nt) * 16 + r16;
      #pragma unroll
      for (int r = 0; r < 4; ++r) {
        float vv = fmaxf(acc3[nt][r] * s4[r] + h4[r], 0.f);
        x3b[(size_t)(c0 + r) * 32768 + n] = f2bf(vv);
      }
    }
  }
}

// ---------------- softmax over K + weighted sum with xyz ----------------
__global__ __launch_bounds__(256) void softmax_ws_kernel(
    const u16* __restrict__ x3, const float* __restrict__ xyz,
    float* __restrict__ out)
{
  const int tid = blockIdx.x * 256 + threadIdx.x;   // 0 .. 524287
  const int b = tid >> 16;
  const int rem = tid & 65535;
  const int d = rem >> 10;
  const int s = rem & 1023;

  const u16* xp = x3 + ((size_t)(b * 64 + d) << 15) + s;
  float p[32];
  float mx = -1e30f;
  #pragma unroll
  for (int k = 0; k < 32; ++k) { p[k] = bf2f(xp[(size_t)k << 10]); mx = fmaxf(mx, p[k]); }
  float sum = 0.f;
  #pragma unroll
  for (int k = 0; k < 32; ++k) { p[k] = __expf(p[k] - mx); sum += p[k]; }
  const float inv = 1.0f / sum;

  const float* zp = xyz + (size_t)b * (3 * 32768) + s;
  #pragma unroll
  for (int c = 0; c < 3; ++c) {
    float a = 0.f;
    #pragma unroll
    for (int k = 0; k < 32; ++k) a += p[k] * zp[c * 32768 + (k << 10)];
    out[((size_t)((b * 3 + c) * 64 + d) << 10) + s] = a * inv;
  }
}

// ---------------- launcher ----------------
extern "C" void kernel_launch(void* const* d_in, const int* in_sizes, int n_in,
                              void* d_out, int out_size, void* d_ws, size_t ws_size,
                              hipStream_t stream) {
  const float* xyz = (const float*)d_in[0];
  const float* gp  = (const float*)d_in[1];
  const float* W0 = (const float*)d_in[2];
  const float* W1 = (const float*)d_in[8];
  const float* W2 = (const float*)d_in[14];
  const float* W3 = (const float*)d_in[20];

  char* ws = (char*)d_ws;
  u16*   Wb = (u16*)ws;                       // 499712 bf16 -> 999424 B
  float* sc = (float*)(ws + 999424);          // 960 f32
  float* sh = (float*)(ws + 1003264);         // 960 f32
  u16*   x3 = (u16*)(ws + 1007104);           // 8*64*32768 bf16 = 33.5 MB

  prep_kernel<<<245, 256, 0, stream>>>(
      W0, W1, W2, W3,
      (const float*)d_in[3],  (const float*)d_in[4],  (const float*)d_in[5],  (const float*)d_in[6],  (const float*)d_in[7],
      (const float*)d_in[9],  (const float*)d_in[10], (const float*)d_in[11], (const float*)d_in[12], (const float*)d_in[13],
      (const float*)d_in[15], (const float*)d_in[16], (const float*)d_in[17], (const float*)d_in[18], (const float*)d_in[19],
      (const float*)d_in[21], (const float*)d_in[22], (const float*)d_in[23], (const float*)d_in[24], (const float*)d_in[25],
      Wb, sc, sh);

  fused4_kernel<<<4096, 512, 0, stream>>>(gp, Wb, sc, sh, x3);

  softmax_ws_kernel<<<2048, 256, 0, stream>>>(x3, xyz, (float*)d_out);
}